// Round 8
// baseline (1537.906 us; speedup 1.0000x reference)
//
#include <hip/hip_runtime.h>
#include <cmath>
#include <cstdint>

namespace {

constexpr int kLevels = 8;
constexpr uint32_t kT = 1u << 16;
constexpr uint32_t kPrime1 = 2654435761u;
constexpr uint32_t kPrime2 = 805459861u;

struct LevelParams {
    float scale[kLevels];
    uint32_t res[kLevels];
    uint32_t hashed_mask;
};

// Round-1 body (fp32 table, 1 pt per iteration, natural 92 VGPR) made
// persistent: 2048 blocks x 256 thr x 4 pts/thread grid-stride.
// Theory: round-1's 22% occupancy (~7 waves/CU, far under the 92-VGPR
// limit of ~20) is workgroup-turnover-rate-limited (8192 short blocks
// ~= 24 WG/us dispatch). Long-lived blocks remove turnover.
// NO min-waves hint (rounds 2/3/5: forced caps spill 0.3-0.9 GB scratch).
// NO LDS (round 6), NO 2pt unroll (round 7: remat inflates VALU 2x).
__global__ __launch_bounds__(256) void ngp_fused_kernel(
    const float* __restrict__ uvi,
    const float* __restrict__ table,
    const float* __restrict__ W1,
    const float* __restrict__ b1,
    const float* __restrict__ W2,
    const float* __restrict__ b2,
    float* __restrict__ out,
    int n, LevelParams lp)
{
    const int stride = gridDim.x * blockDim.x;
    const float2* __restrict__ tb = reinterpret_cast<const float2*>(table);

    #pragma unroll 1
    for (int i = blockIdx.x * blockDim.x + threadIdx.x; i < n; i += stride) {
        const float ux = uvi[3 * i + 0];
        const float uy = uvi[3 * i + 1];
        const float uz = uvi[3 * i + 2];

        float enc[16];

        #pragma unroll
        for (int l = 0; l < kLevels; ++l) {
            const float s = lp.scale[l];
            const float px = fmaf(ux, s, 0.5f);
            const float py = fmaf(uy, s, 0.5f);
            const float pz = fmaf(uz, s, 0.5f);
            const float fx = floorf(px), fy = floorf(py), fz = floorf(pz);
            const float wx = px - fx, wy = py - fy, wz = pz - fz;
            const uint32_t x0 = (uint32_t)fx, y0 = (uint32_t)fy, z0 = (uint32_t)fz;

            const bool hashed = (lp.hashed_mask >> l) & 1u;

            uint32_t hx0, hx1, hy0, hy1, hz0, hz1;
            if (hashed) {
                hx0 = x0;             hx1 = x0 + 1u;
                hy0 = y0 * kPrime1;   hy1 = hy0 + kPrime1;
                hz0 = z0 * kPrime2;   hz1 = hz0 + kPrime2;
            } else {
                const uint32_t r  = lp.res[l];
                const uint32_t r2 = r * r;
                hx0 = x0;             hx1 = x0 + 1u;
                hy0 = y0 * r;         hy1 = hy0 + r;
                hz0 = z0 * r2;        hz1 = hz0 + r2;
            }

            const float wx0 = 1.f - wx, wy0 = 1.f - wy, wz0 = 1.f - wz;
            const float w00 = wx0 * wy0;
            const float w10 = wx  * wy0;
            const float w01 = wx0 * wy;
            const float w11 = wx  * wy;

            const uint32_t base = (uint32_t)l << 16;
            float a0 = 0.f, a1 = 0.f;

            #pragma unroll
            for (int c = 0; c < 8; ++c) {
                const uint32_t hx = (c & 1) ? hx1 : hx0;
                const uint32_t hy = (c & 2) ? hy1 : hy0;
                const uint32_t hz = (c & 4) ? hz1 : hz0;
                uint32_t idxc;
                if (hashed) idxc = (hx ^ hy ^ hz) & (kT - 1u);
                else        idxc = hx + hy + hz;
                const float wxy = (c & 2) ? ((c & 1) ? w11 : w01)
                                          : ((c & 1) ? w10 : w00);
                const float wcc = wxy * ((c & 4) ? wz : wz0);
                const float2 t = tb[base + idxc];
                a0 = fmaf(t.x, wcc, a0);
                a1 = fmaf(t.y, wcc, a1);
            }
            enc[2 * l + 0] = a0;
            enc[2 * l + 1] = a1;
        }

        // MLP: weights at compile-time indices -> uniform scalar loads
        float logit = b2[0];
        #pragma unroll
        for (int j = 0; j < 64; ++j) {
            float h = b1[j];
            #pragma unroll
            for (int k = 0; k < 16; ++k)
                h = fmaf(enc[k], W1[k * 64 + j], h);
            h = fmaxf(h, 0.f);
            logit = fmaf(h, W2[j], logit);
        }

        out[i] = 1.f / (1.f + __expf(-logit));
    }
}

} // namespace

extern "C" void kernel_launch(void* const* d_in, const int* in_sizes, int n_in,
                              void* d_out, int out_size, void* d_ws, size_t ws_size,
                              hipStream_t stream)
{
    const float* uvi   = (const float*)d_in[0];
    const float* table = (const float*)d_in[1];
    const float* W1    = (const float*)d_in[2];
    const float* b1    = (const float*)d_in[3];
    const float* W2    = (const float*)d_in[4];
    const float* b2    = (const float*)d_in[5];
    float* out = (float*)d_out;

    const int n = in_sizes[0] / 3;

    // Replicate numpy's double-precision level math exactly.
    LevelParams lp;
    const double B = exp(log(2048.0 / 16.0) / (double)(kLevels - 1));
    uint32_t mask = 0;
    for (int l = 0; l < kLevels; ++l) {
        const double scale_d = 16.0 * pow(B, (double)l) - 1.0;
        const long long res = (long long)ceil(scale_d) + 1;
        lp.scale[l] = (float)scale_d;
        lp.res[l]   = (uint32_t)res;
        if (res * res * res > (long long)kT) mask |= (1u << l);
    }
    lp.hashed_mask = mask;

    // 2048 blocks x 256 threads x 4 points/thread == 2,097,152 exactly.
    dim3 block(256);
    dim3 grid(2048);
    hipLaunchKernelGGL(ngp_fused_kernel, grid, block, 0, stream,
                       uvi, table, W1, b1, W2, b2, out, n, lp);
}

// Round 9
// 556.348 us; speedup vs baseline: 2.7643x; 2.7643x over previous
//
#include <hip/hip_runtime.h>
#include <cmath>
#include <cstdint>

namespace {

constexpr int kLevels = 8;
constexpr uint32_t kT = 1u << 16;
constexpr uint32_t kPrime1 = 2654435761u;
constexpr uint32_t kPrime2 = 805459861u;

struct LevelParams {
    float scale[kLevels];
    uint32_t res[kLevels];
    uint32_t hashed_mask;
};

// Round-1 body, ONE config flip: 1024-thread blocks (16 waves/block).
// Theory: clean runs pin at ~22% occupancy ~= 1.75 resident 4-wave blocks/CU
// -> suspect a block-residency cap, so pack 16 waves per block instead.
// Deliberately NO __launch_bounds__: default flat-workgroup cap (1024)
// bounds VGPR at 128 >= natural 92 -> no forced-cap spill (the rounds-2/3/5
// failures were min-waves hints). No LDS (r6), no multi-point (r7), no
// grid-stride loop (r8) -- every shape deviation regressed.
__global__ void ngp_fused_kernel(
    const float* __restrict__ uvi,
    const float* __restrict__ table,
    const float* __restrict__ W1,
    const float* __restrict__ b1,
    const float* __restrict__ W2,
    const float* __restrict__ b2,
    float* __restrict__ out,
    int n, LevelParams lp)
{
    const int i = blockIdx.x * blockDim.x + threadIdx.x;
    if (i >= n) return;

    const float ux = uvi[3 * i + 0];
    const float uy = uvi[3 * i + 1];
    const float uz = uvi[3 * i + 2];

    const float2* __restrict__ tb = reinterpret_cast<const float2*>(table);

    float enc[16];

    #pragma unroll
    for (int l = 0; l < kLevels; ++l) {
        const float s = lp.scale[l];
        const float px = fmaf(ux, s, 0.5f);
        const float py = fmaf(uy, s, 0.5f);
        const float pz = fmaf(uz, s, 0.5f);
        const float fx = floorf(px), fy = floorf(py), fz = floorf(pz);
        const float wx = px - fx, wy = py - fy, wz = pz - fz;
        const uint32_t x0 = (uint32_t)fx, y0 = (uint32_t)fy, z0 = (uint32_t)fz;

        const bool hashed = (lp.hashed_mask >> l) & 1u;

        uint32_t hx0, hx1, hy0, hy1, hz0, hz1;
        if (hashed) {
            hx0 = x0;             hx1 = x0 + 1u;
            hy0 = y0 * kPrime1;   hy1 = hy0 + kPrime1;
            hz0 = z0 * kPrime2;   hz1 = hz0 + kPrime2;
        } else {
            const uint32_t r  = lp.res[l];
            const uint32_t r2 = r * r;
            hx0 = x0;             hx1 = x0 + 1u;
            hy0 = y0 * r;         hy1 = hy0 + r;
            hz0 = z0 * r2;        hz1 = hz0 + r2;
        }

        const float wx0 = 1.f - wx, wy0 = 1.f - wy, wz0 = 1.f - wz;
        const float w00 = wx0 * wy0;
        const float w10 = wx  * wy0;
        const float w01 = wx0 * wy;
        const float w11 = wx  * wy;

        const uint32_t base = (uint32_t)l << 16;
        float a0 = 0.f, a1 = 0.f;

        #pragma unroll
        for (int c = 0; c < 8; ++c) {
            const uint32_t hx = (c & 1) ? hx1 : hx0;
            const uint32_t hy = (c & 2) ? hy1 : hy0;
            const uint32_t hz = (c & 4) ? hz1 : hz0;
            uint32_t idxc;
            if (hashed) idxc = (hx ^ hy ^ hz) & (kT - 1u);
            else        idxc = hx + hy + hz;
            const float wxy = (c & 2) ? ((c & 1) ? w11 : w01)
                                      : ((c & 1) ? w10 : w00);
            const float wcc = wxy * ((c & 4) ? wz : wz0);
            const float2 t = tb[base + idxc];
            a0 = fmaf(t.x, wcc, a0);
            a1 = fmaf(t.y, wcc, a1);
        }
        enc[2 * l + 0] = a0;
        enc[2 * l + 1] = a1;
    }

    // MLP: weights at compile-time indices -> uniform scalar loads
    float logit = b2[0];
    #pragma unroll
    for (int j = 0; j < 64; ++j) {
        float h = b1[j];
        #pragma unroll
        for (int k = 0; k < 16; ++k)
            h = fmaf(enc[k], W1[k * 64 + j], h);
        h = fmaxf(h, 0.f);
        logit = fmaf(h, W2[j], logit);
    }

    out[i] = 1.f / (1.f + __expf(-logit));
}

} // namespace

extern "C" void kernel_launch(void* const* d_in, const int* in_sizes, int n_in,
                              void* d_out, int out_size, void* d_ws, size_t ws_size,
                              hipStream_t stream)
{
    const float* uvi   = (const float*)d_in[0];
    const float* table = (const float*)d_in[1];
    const float* W1    = (const float*)d_in[2];
    const float* b1    = (const float*)d_in[3];
    const float* W2    = (const float*)d_in[4];
    const float* b2    = (const float*)d_in[5];
    float* out = (float*)d_out;

    const int n = in_sizes[0] / 3;

    // Replicate numpy's double-precision level math exactly.
    LevelParams lp;
    const double B = exp(log(2048.0 / 16.0) / (double)(kLevels - 1));
    uint32_t mask = 0;
    for (int l = 0; l < kLevels; ++l) {
        const double scale_d = 16.0 * pow(B, (double)l) - 1.0;
        const long long res = (long long)ceil(scale_d) + 1;
        lp.scale[l] = (float)scale_d;
        lp.res[l]   = (uint32_t)res;
        if (res * res * res > (long long)kT) mask |= (1u << l);
    }
    lp.hashed_mask = mask;

    dim3 block(1024);
    dim3 grid((unsigned)((n + 1023) / 1024));
    hipLaunchKernelGGL(ngp_fused_kernel, grid, block, 0, stream,
                       uvi, table, W1, b1, W2, b2, out, n, lp);
}